// Round 1
// baseline (293.696 us; speedup 1.0000x reference)
//
#include <hip/hip_runtime.h>

namespace {

constexpr int BD = 2;
constexpr int DD = 160, HH = 192, WW = 224;
constexpr int PADR = 4;
constexpr float INV_WIN = 1.0f / 729.0f;
constexpr float EPSV = 1e-5f;

constexpr int TH = 16, TW = 16;          // output tile (H x W)
constexpr int IH = TH + 8, IW = TW + 8;  // 24 x 24 input tile (halo 4 each side)
constexpr int DC = 80;                   // output planes per d-chunk
constexpr int NSTEP = 90;                // DC + 8 halo, padded to multiple of 9
constexpr int GX = WW / TW;              // 14
constexpr int GY = HH / TH;              // 12
constexpr int GZ = BD * (DD / DC);       // 4
constexpr int NBLK = GX * GY * GZ;       // 672
constexpr double NTOT = (double)BD * DD * HH * WW;

} // namespace

__global__ __launch_bounds__(256)
void ncc_fused(const float* __restrict__ x, const float* __restrict__ y,
               float* __restrict__ bsum) {
  const int tid = threadIdx.x;
  const int w0 = blockIdx.x * TW;
  const int h0 = blockIdx.y * TH;
  const int b  = blockIdx.z >> 1;
  const int d0 = (blockIdx.z & 1) * DC;

  __shared__ float sx[IH][IW];
  __shared__ float sy[IH][IW];
  __shared__ float srow[IH][TW][6];   // W-sums: [row][w_out][field], pad 6 (2-way max, free)
  __shared__ float scol[TH][TW][6];   // 2D sums handoff
  __shared__ float swsum[4];

  const int ow = tid & 15;   // this thread's output column (h0+oh, w0+ow)
  const int oh = tid >> 4;

  // D-direction ring buffers (9 planes x 5 fields) in registers; static
  // indexing guaranteed by the fully-unrolled inner j-loop.
  float r0[9], r1[9], r2[9], r3[9], r4[9];
#pragma unroll
  for (int j = 0; j < 9; ++j) { r0[j]=0.f; r1[j]=0.f; r2[j]=0.f; r3[j]=0.f; r4[j]=0.f; }
  float a0=0.f, a1=0.f, a2=0.f, a3=0.f, a4=0.f;
  float lsum = 0.0f;

  for (int base = 0; base < NSTEP; base += 9) {
#pragma unroll
    for (int j = 0; j < 9; ++j) {
      const int step = base + j;
      const int din = d0 - PADR + step;     // input plane this step
      const bool dok = (din >= 0) && (din < DD);

      // ---- S1: stage input plane tile (zero-padded) into LDS
      const unsigned pbase = ((unsigned)b * DD + (unsigned)(dok ? din : 0)) * (HH * WW);
#pragma unroll
      for (int it = 0; it < 3; ++it) {
        const int i = tid + it * 256;
        if (i < IH * IW) {
          const int rr = i / IW, cc = i - rr * IW;
          const int gh = h0 - PADR + rr;
          const int gw = w0 - PADR + cc;
          float xv = 0.0f, yv = 0.0f;
          if (dok && (unsigned)gh < (unsigned)HH && (unsigned)gw < (unsigned)WW) {
            const unsigned idx = pbase + (unsigned)gh * WW + (unsigned)gw;
            xv = x[idx]; yv = y[idx];
          }
          sx[rr][cc] = xv; sy[rr][cc] = yv;
        }
      }
      __syncthreads();

      // ---- S2: sliding 9-tap W-sums of the 5 fields; 24 rows x 4 segments
      if (tid < 96) {
        const int rr = tid >> 2;
        const int c0 = (tid & 3) << 2;   // 4 outputs per segment
        float xv[12], yv[12];
#pragma unroll
        for (int k = 0; k < 12; ++k) { xv[k] = sx[rr][c0 + k]; yv[k] = sy[rr][c0 + k]; }
        float s0=0.f, s1=0.f, s2=0.f, s3=0.f, s4=0.f;
#pragma unroll
        for (int k = 0; k < 9; ++k) {
          s0 += xv[k]; s1 += yv[k];
          s2 = fmaf(xv[k], xv[k], s2);
          s3 = fmaf(yv[k], yv[k], s3);
          s4 = fmaf(xv[k], yv[k], s4);
        }
        srow[rr][c0][0]=s0; srow[rr][c0][1]=s1; srow[rr][c0][2]=s2;
        srow[rr][c0][3]=s3; srow[rr][c0][4]=s4;
#pragma unroll
        for (int t = 1; t < 4; ++t) {
          const int kn = 8 + t, ko = t - 1;
          s0 += xv[kn] - xv[ko];
          s1 += yv[kn] - yv[ko];
          s2 += fmaf(xv[kn], xv[kn], -(xv[ko]*xv[ko]));
          s3 += fmaf(yv[kn], yv[kn], -(yv[ko]*yv[ko]));
          s4 += fmaf(xv[kn], yv[kn], -(xv[ko]*yv[ko]));
          srow[rr][c0+t][0]=s0; srow[rr][c0+t][1]=s1; srow[rr][c0+t][2]=s2;
          srow[rr][c0+t][3]=s3; srow[rr][c0+t][4]=s4;
        }
      }
      __syncthreads();

      // ---- S3: sliding 9-tap H-sums; 16 w-columns x 5 fields = 80 jobs
      if (tid < 80) {
        const int w = tid & 15;
        const int f = tid >> 4;
        float s = 0.0f;
#pragma unroll
        for (int rr = 0; rr < 8; ++rr) s += srow[rr][w][f];
#pragma unroll
        for (int o = 0; o < TH; ++o) {
          s += srow[o + 8][w][f];
          scol[o][w][f] = s;
          s -= srow[o][w][f];
        }
      }
      __syncthreads();

      // ---- S4: per-thread D ring update + emit
      const float g0 = scol[oh][ow][0];
      const float g1 = scol[oh][ow][1];
      const float g2 = scol[oh][ow][2];
      const float g3 = scol[oh][ow][3];
      const float g4 = scol[oh][ow][4];
      a0 += g0 - r0[j]; r0[j] = g0;
      a1 += g1 - r1[j]; r1[j] = g1;
      a2 += g2 - r2[j]; r2[j] = g2;
      a3 += g3 - r3[j]; r3[j] = g3;
      a4 += g4 - r4[j]; r4[j] = g4;
      if (step >= 8 && step < DC + 8) {
        const float cross = fmaf(-a0 * INV_WIN, a1, a4);
        const float iv = fmaxf(fmaf(-a0 * INV_WIN, a0, a2), EPSV);
        const float jv = fmaxf(fmaf(-a1 * INV_WIN, a1, a3), EPSV);
        lsum += (cross * cross) / (iv * jv);
      }
      // no barrier needed here: next S1 touches only sx/sy (readers already
      // past the S2 barrier), and scol is next written only after 2 barriers.
    }
  }

  // ---- block reduction
#pragma unroll
  for (int off = 32; off > 0; off >>= 1) lsum += __shfl_down(lsum, off);
  if ((tid & 63) == 0) swsum[tid >> 6] = lsum;
  __syncthreads();
  if (tid == 0) {
    const int bid = ((int)blockIdx.z * GY + (int)blockIdx.y) * GX + (int)blockIdx.x;
    bsum[bid] = swsum[0] + swsum[1] + swsum[2] + swsum[3];
  }
}

__global__ __launch_bounds__(256)
void ncc_finalize(const float* __restrict__ bsum, float* __restrict__ out) {
  double s = 0.0;
  for (int i = threadIdx.x; i < NBLK; i += 256) s += (double)bsum[i];
#pragma unroll
  for (int off = 32; off > 0; off >>= 1) s += __shfl_down(s, off);
  __shared__ double sh[4];
  if ((threadIdx.x & 63) == 0) sh[threadIdx.x >> 6] = s;
  __syncthreads();
  if (threadIdx.x == 0)
    out[0] = (float)(-(sh[0] + sh[1] + sh[2] + sh[3]) / NTOT);
}

extern "C" void kernel_launch(void* const* d_in, const int* in_sizes, int n_in,
                              void* d_out, int out_size, void* d_ws, size_t ws_size,
                              hipStream_t stream) {
  const float* x = (const float*)d_in[0];
  const float* y = (const float*)d_in[1];
  float* bsum = (float*)d_ws;          // 672 floats, rewritten every call
  float* out  = (float*)d_out;

  dim3 grid(GX, GY, GZ);
  ncc_fused<<<grid, dim3(256), 0, stream>>>(x, y, bsum);
  ncc_finalize<<<1, dim3(256), 0, stream>>>(bsum, out);
}

// Round 2
// 223.206 us; speedup vs baseline: 1.3158x; 1.3158x over previous
//
#include <hip/hip_runtime.h>

namespace {

constexpr int BD = 2;
constexpr int DD = 160, HH = 192, WW = 224;
constexpr int PADR = 4;
constexpr float INV_WIN = 1.0f / 729.0f;
constexpr float EPSV = 1e-5f;

constexpr int TH = 16, TW = 16;          // output tile (H x W)
constexpr int IH = TH + 8, IW = TW + 8;  // 24 x 24 staged input tile
constexpr int LW = IW + 1;               // 25: sx/sy LDS row stride (bank spread)
constexpr int RS = TW * 6 + 4;           // 100: srow row stride (100%32=4 spreads rows)
constexpr int DC = 32;                   // output planes per d-chunk
constexpr int NREAL = DC + 8;            // 40 real steps
constexpr int NCH = DD / DC;             // 5 chunks
constexpr int GX = WW / TW;              // 14
constexpr int GY = HH / TH;              // 12
constexpr int GZ = BD * NCH;             // 10
constexpr int NBLK = GX * GY * GZ;       // 1680
constexpr double NTOT = (double)BD * DD * HH * WW;

} // namespace

__global__ __launch_bounds__(256)
void ncc_fused(const float* __restrict__ x, const float* __restrict__ y,
               float* __restrict__ bsum) {
  const int tid = threadIdx.x;
  const int w0 = blockIdx.x * TW;
  const int h0 = blockIdx.y * TH;
  const int zb = blockIdx.z;
  const int b  = zb / NCH;
  const int d0 = (zb - b * NCH) * DC;

  __shared__ float sx[IH * LW];
  __shared__ float sy[IH * LW];
  __shared__ float srow[IH * RS];           // W-sums: row-major, 5 fields per out col
  __shared__ float scol[5][TH][TW + 1];     // 2D sums handoff, field-major
  __shared__ float swsum[4];

  // ---- per-thread staging geometry (step-invariant, hoisted) ----
  bool sok[3], sval[3];
  unsigned poff[3];
  int lofs[3];
#pragma unroll
  for (int it = 0; it < 3; ++it) {
    const int i = tid + it * 256;
    const int rr = i / IW, cc = i - rr * IW;
    const int gh = h0 - PADR + rr;
    const int gw = w0 - PADR + cc;
    sok[it]  = (i < IH * IW);
    sval[it] = sok[it] && ((unsigned)gh < (unsigned)HH) && ((unsigned)gw < (unsigned)WW);
    poff[it] = (unsigned)(gh * WW + gw);   // only dereferenced when sval
    lofs[it] = rr * LW + cc;
  }

  const unsigned batch = (unsigned)b * DD * (HH * WW);

  auto prefetch = [&](int s, float (&px)[3], float (&py)[3]) {
    const int din = d0 - PADR + s;
    const bool dok = (din >= 0) && (din < DD) && (s < NREAL);
    const unsigned pb = batch + (unsigned)(dok ? din : 0) * (HH * WW);
#pragma unroll
    for (int it = 0; it < 3; ++it) {
      px[it] = 0.0f; py[it] = 0.0f;
      if (dok && sval[it]) {
        px[it] = x[pb + poff[it]];
        py[it] = y[pb + poff[it]];
      }
    }
  };

  const int ow = tid & 15;
  const int oh = tid >> 4;

  // D-direction ring buffers (9 planes x 5 fields) in registers; static
  // indexing guaranteed by the fully-unrolled inner j-loop.
  float r0[9], r1[9], r2[9], r3[9], r4[9];
#pragma unroll
  for (int j = 0; j < 9; ++j) { r0[j]=0.f; r1[j]=0.f; r2[j]=0.f; r3[j]=0.f; r4[j]=0.f; }
  float a0=0.f, a1=0.f, a2=0.f, a3=0.f, a4=0.f;
  float lsum = 0.0f;

  float px[3], py[3];
  prefetch(0, px, py);

  for (int base = 0; base < 45; base += 9) {
#pragma unroll
    for (int j = 0; j < 9; ++j) {
      const int step = base + j;
      if (step < NREAL) {     // uniform guard (tail of last 9-chunk skipped)
        // issue next plane's global loads first (latency hidden behind S2-S4)
        float nx[3], ny[3];
        prefetch(step + 1, nx, ny);

        // commit previously-prefetched plane to LDS (waits only on px/py)
#pragma unroll
        for (int it = 0; it < 3; ++it) {
          if (sok[it]) { sx[lofs[it]] = px[it]; sy[lofs[it]] = py[it]; }
        }
        __syncthreads();   // A: sx/sy visible

        // ---- S2: sliding 9-tap W-sums; 24 rows x 8 segments x 2 outputs
        if (tid < 192) {
          const int rr = tid >> 3;
          const int c0 = (tid & 7) * 2;
          const float* rx = &sx[rr * LW + c0];
          const float* ry = &sy[rr * LW + c0];
          float xv[10], yv[10];
#pragma unroll
          for (int k = 0; k < 10; ++k) { xv[k] = rx[k]; yv[k] = ry[k]; }
          float s0=0.f, s1=0.f, s2=0.f, s3=0.f, s4=0.f;
#pragma unroll
          for (int k = 0; k < 9; ++k) {
            s0 += xv[k]; s1 += yv[k];
            s2 = fmaf(xv[k], xv[k], s2);
            s3 = fmaf(yv[k], yv[k], s3);
            s4 = fmaf(xv[k], yv[k], s4);
          }
          float* wr = &srow[rr * RS + c0 * 6];
          wr[0]=s0; wr[1]=s1; wr[2]=s2; wr[3]=s3; wr[4]=s4;
          s0 += xv[9] - xv[0];
          s1 += yv[9] - yv[0];
          s2 += fmaf(xv[9], xv[9], -(xv[0]*xv[0]));
          s3 += fmaf(yv[9], yv[9], -(yv[0]*yv[0]));
          s4 += fmaf(xv[9], yv[9], -(xv[0]*yv[0]));
          wr[6]=s0; wr[7]=s1; wr[8]=s2; wr[9]=s3; wr[10]=s4;
        }
        __syncthreads();   // B

        // ---- S3: sliding 9-tap H-sums; 16 cols x 5 fields x 2 halves
        if (tid < 160) {
          const int w = tid & 15;
          const int q = tid >> 4;      // 0..9
          const int f = q >> 1;
          const int o0 = (q & 1) * 8;
          const float* cr = &srow[w * 6 + f];
          float s = 0.0f;
#pragma unroll
          for (int rr = 0; rr < 8; ++rr) s += cr[(o0 + rr) * RS];
#pragma unroll
          for (int t = 0; t < 8; ++t) {
            const int o = o0 + t;
            s += cr[(o + 8) * RS];
            scol[f][o][w] = s;
            s -= cr[o * RS];
          }
        }
        __syncthreads();   // C

        // ---- S4: per-thread D ring update + emit (all 256 threads)
        const float g0 = scol[0][oh][ow];
        const float g1 = scol[1][oh][ow];
        const float g2 = scol[2][oh][ow];
        const float g3 = scol[3][oh][ow];
        const float g4 = scol[4][oh][ow];
        a0 += g0 - r0[j]; r0[j] = g0;
        a1 += g1 - r1[j]; r1[j] = g1;
        a2 += g2 - r2[j]; r2[j] = g2;
        a3 += g3 - r3[j]; r3[j] = g3;
        a4 += g4 - r4[j]; r4[j] = g4;
        if (step >= 8) {
          const float cross = fmaf(-a0 * INV_WIN, a1, a4);
          const float iv = fmaxf(fmaf(-a0 * INV_WIN, a0, a2), EPSV);
          const float jv = fmaxf(fmaf(-a1 * INV_WIN, a1, a3), EPSV);
          lsum += (cross * cross) / (iv * jv);
        }
        // no barrier needed: next sx/sy writes happen after barrier C for
        // every thread, and S2 readers of the old plane finished before B.
#pragma unroll
        for (int it = 0; it < 3; ++it) { px[it] = nx[it]; py[it] = ny[it]; }
      }
    }
  }

  // ---- block reduction
#pragma unroll
  for (int off = 32; off > 0; off >>= 1) lsum += __shfl_down(lsum, off);
  if ((tid & 63) == 0) swsum[tid >> 6] = lsum;
  __syncthreads();
  if (tid == 0) {
    const int bid = ((int)blockIdx.z * GY + (int)blockIdx.y) * GX + (int)blockIdx.x;
    bsum[bid] = swsum[0] + swsum[1] + swsum[2] + swsum[3];
  }
}

__global__ __launch_bounds__(256)
void ncc_finalize(const float* __restrict__ bsum, float* __restrict__ out) {
  double s = 0.0;
  for (int i = threadIdx.x; i < NBLK; i += 256) s += (double)bsum[i];
#pragma unroll
  for (int off = 32; off > 0; off >>= 1) s += __shfl_down(s, off);
  __shared__ double sh[4];
  if ((threadIdx.x & 63) == 0) sh[threadIdx.x >> 6] = s;
  __syncthreads();
  if (threadIdx.x == 0)
    out[0] = (float)(-(sh[0] + sh[1] + sh[2] + sh[3]) / NTOT);
}

extern "C" void kernel_launch(void* const* d_in, const int* in_sizes, int n_in,
                              void* d_out, int out_size, void* d_ws, size_t ws_size,
                              hipStream_t stream) {
  const float* x = (const float*)d_in[0];
  const float* y = (const float*)d_in[1];
  float* bsum = (float*)d_ws;          // 1680 floats, rewritten every call
  float* out  = (float*)d_out;

  dim3 grid(GX, GY, GZ);
  ncc_fused<<<grid, dim3(256), 0, stream>>>(x, y, bsum);
  ncc_finalize<<<1, dim3(256), 0, stream>>>(bsum, out);
}